// Round 5
// baseline (124.661 us; speedup 1.0000x reference)
//
#include <hip/hip_runtime.h>
#include <stdint.h>

#define B_ 8
#define N_ 4096
#define D_ 512
#define INV_T 0.04419417382415922f  // 1/sqrt(512)

typedef unsigned short u16;
typedef float f32x4 __attribute__((ext_vector_type(4)));
typedef __bf16 bf16x4 __attribute__((ext_vector_type(4)));
typedef __bf16 bf16x8 __attribute__((ext_vector_type(8)));
typedef unsigned short u16x8 __attribute__((ext_vector_type(8)));

__device__ __forceinline__ u16 f2bf(float x) {
  union { float f; uint32_t u; } c;
  c.f = x;
  uint32_t r = c.u + 0x7FFFu + ((c.u >> 16) & 1u);
  return (u16)(r >> 16);
}

__device__ __forceinline__ void load_lds16(const u16* g, u16* l) {
  __builtin_amdgcn_global_load_lds(
      (__attribute__((address_space(1))) void*)(g),
      (__attribute__((address_space(3))) void*)(l), 16, 0, 0);
}

// Fused transpose+gemm1: Sp[kz*8+b][d][e] = sum_{n in kz slice} k[b][n][d]*v[b][n][e]
// (unscaled; 1/T folded into softmax). 8-way split-K (512 n per slice).
__global__ __launch_bounds__(256) void k_gemm1f(const float* __restrict__ kin,
                                                const float* __restrict__ vin,
                                                float* __restrict__ Sp) {
  __shared__ u16 As[128 * 32];  // [d_local][n_local], write-XOR-swizzled
  __shared__ u16 Bs[128 * 32];  // [e_local][n_local], write-XOR-swizzled
  const int bm = blockIdx.x, bn = blockIdx.y, z = blockIdx.z;
  const int b = z & 7, kz = z >> 3;  // split-K = 8, 512 n per slice
  const int tid = threadIdx.x;
  const int wave = tid >> 6, lane = tid & 63;
  const int wr = wave >> 1, wc = wave & 1;
  const int lrow = lane & 15, lk = (lane >> 4) * 8;
  const int c = tid & 31, G = tid >> 5;  // c: d-chunk (4 cols), G: n-group (4 rows)
  const float* ga = kin + (size_t)b * N_ * D_ + (size_t)(kz * 512 + 4 * G) * D_ +
                    bm * 128 + 4 * c;
  const float* gb = vin + (size_t)b * N_ * D_ + (size_t)(kz * 512 + 4 * G) * D_ +
                    bn * 128 + 4 * c;
  float* C = Sp + (size_t)z * ((size_t)D_ * D_);

  const f32x4 fzero = {0.f, 0.f, 0.f, 0.f};
  f32x4 acc[4][4];
#pragma unroll
  for (int m = 0; m < 4; ++m)
#pragma unroll
    for (int n = 0; n < 4; ++n) acc[m][n] = fzero;

  f32x4 ra[4], rb[4];
#pragma unroll
  for (int j = 0; j < 4; ++j) {
    ra[j] = *(const f32x4*)(ga + (size_t)j * D_);
    rb[j] = *(const f32x4*)(gb + (size_t)j * D_);
  }

  for (int kt = 0; kt < 16; ++kt) {
    bf16x4 wav[4], wbv[4];  // register 4x4 transpose + cvt
#pragma unroll
    for (int i = 0; i < 4; ++i) {
#pragma unroll
      for (int j = 0; j < 4; ++j) {
        wav[i][j] = (__bf16)ra[j][i];
        wbv[i][j] = (__bf16)rb[j][i];
      }
    }
    __syncthreads();  // previous iteration's fragment reads complete
#pragma unroll
    for (int i = 0; i < 4; ++i) {
      // d_local = 4c+i; swizzle idx ^= ((d_local>>2)&7)<<3 == ((c&7)<<3)
      const int sidx = ((4 * c + i) * 32 + 4 * G) ^ ((c & 7) << 3);
      *(bf16x4*)(As + sidx) = wav[i];
      *(bf16x4*)(Bs + sidx) = wbv[i];
    }
    __syncthreads();  // writes visible
    if (kt + 1 < 16) {
#pragma unroll
      for (int j = 0; j < 4; ++j) {  // prefetch next step; drains at next barrier
        ra[j] = *(const f32x4*)(ga + (size_t)((kt + 1) * 32 + j) * D_);
        rb[j] = *(const f32x4*)(gb + (size_t)((kt + 1) * 32 + j) * D_);
      }
    }
    bf16x8 af[4], bfv[4];
#pragma unroll
    for (int m = 0; m < 4; ++m) {
      const int row = wr * 64 + m * 16 + lrow;
      af[m] = *(const bf16x8*)(As + ((row * 32 + lk) ^ (((row >> 2) & 7) << 3)));
    }
#pragma unroll
    for (int n = 0; n < 4; ++n) {
      const int row = wc * 64 + n * 16 + lrow;
      bfv[n] = *(const bf16x8*)(Bs + ((row * 32 + lk) ^ (((row >> 2) & 7) << 3)));
    }
#pragma unroll
    for (int m = 0; m < 4; ++m)
#pragma unroll
      for (int n = 0; n < 4; ++n)
        acc[m][n] = __builtin_amdgcn_mfma_f32_16x16x32_bf16(af[m], bfv[n],
                                                            acc[m][n], 0, 0, 0);
  }
  // C/D layout (m89-verified): row = (lane>>4)*4 + reg, col = lane&15
  const int crow = (lane >> 4) * 4, ccol = lane & 15;
#pragma unroll
  for (int m = 0; m < 4; ++m) {
    const int grow = bm * 128 + wr * 64 + m * 16 + crow;
#pragma unroll
    for (int n = 0; n < 4; ++n) {
      const int gcol = bn * 128 + wc * 64 + n * 16 + ccol;
#pragma unroll
      for (int i2 = 0; i2 < 4; ++i2)
        C[(size_t)(grow + i2) * D_ + gcol] = acc[m][n][i2];
    }
  }
}

// Sum 8 split-K partials, scale by 1/T, softmax rows, write attn fp32.
__global__ __launch_bounds__(256) void k_softmax(const float* __restrict__ Sp,
                                                 float* __restrict__ attn) {
  const int t = threadIdx.x;
  const int wave = t >> 6, lane = t & 63;
  const int g = blockIdx.x * 4 + wave;  // 0..4095 rows
  const int b = g >> 9, d = g & 511;
  const float* base = Sp + (size_t)b * (D_ * D_) + (size_t)d * D_ + lane * 8;
  float s[8];
#pragma unroll
  for (int jj = 0; jj < 8; ++jj) s[jj] = 0.f;
#pragma unroll
  for (int kz = 0; kz < 8; ++kz) {
    const f32x4 p0 = *(const f32x4*)(base + (size_t)kz * 8 * (D_ * D_));
    const f32x4 p1 = *(const f32x4*)(base + (size_t)kz * 8 * (D_ * D_) + 4);
#pragma unroll
    for (int jj = 0; jj < 4; ++jj) { s[jj] += p0[jj]; s[4 + jj] += p1[jj]; }
  }
#pragma unroll
  for (int jj = 0; jj < 8; ++jj) s[jj] *= INV_T;  // temperature
  float mx = s[0];
#pragma unroll
  for (int jj = 1; jj < 8; ++jj) mx = fmaxf(mx, s[jj]);
  for (int o = 32; o > 0; o >>= 1) mx = fmaxf(mx, __shfl_xor(mx, o));
  float sum = 0.f;
#pragma unroll
  for (int jj = 0; jj < 8; ++jj) { s[jj] = __expf(s[jj] - mx); sum += s[jj]; }
  for (int o = 32; o > 0; o >>= 1) sum += __shfl_xor(sum, o);
  const float inv = 1.0f / sum;
  float* orow = attn + (size_t)b * (D_ * D_) + (size_t)d * D_ + lane * 8;
  f32x4 o0, o1;
#pragma unroll
  for (int jj = 0; jj < 4; ++jj) { o0[jj] = s[jj] * inv; o1[jj] = s[4 + jj] * inv; }
  *(f32x4*)orow = o0;
  *(f32x4*)(orow + 4) = o1;
}

// attn fp32 [b][d][e] -> attnT bf16 [b][e][d]
__global__ __launch_bounds__(256) void k_attn_t(const float* __restrict__ attn,
                                                u16* __restrict__ attnT) {
  __shared__ float lds[64][65];
  const int t = threadIdx.x;
  const int b = blockIdx.z;
  const float* src = attn + (size_t)b * D_ * D_;
  u16* dst = attnT + (size_t)b * D_ * D_;
  const int d0 = blockIdx.x * 64, e0 = blockIdx.y * 64;
#pragma unroll
  for (int i = 0; i < 4; ++i) {
    const int fidx = i * 256 + t;
    const int r = fidx >> 4, c4 = fidx & 15;
    const f32x4 f = *(const f32x4*)(src + (size_t)(d0 + r) * D_ + e0 + c4 * 4);
#pragma unroll
    for (int jj = 0; jj < 4; ++jj) lds[r][c4 * 4 + jj] = f[jj];
  }
  __syncthreads();
#pragma unroll
  for (int j = 0; j < 2; ++j) {
    const int sidx = j * 256 + t;
    const int rd = sidx >> 3, c8 = sidx & 7;
    u16x8 o;
#pragma unroll
    for (int jj = 0; jj < 8; ++jj) o[jj] = f2bf(lds[c8 * 8 + jj][rd]);
    *(u16x8*)(dst + (size_t)(e0 + rd) * D_ + d0 + c8 * 8) = o;
  }
}

// gemm2: out[b][n][e] = sum_d v[b][n][d] * attnT[b][e][d]
__global__ __launch_bounds__(256) void k_gemm2(const float* __restrict__ v,
                                               const u16* __restrict__ attnT,
                                               float* __restrict__ out) {
  __shared__ u16 As[128 * 32];
  __shared__ u16 Bs[128 * 32];
  const int bm = blockIdx.x, bn = blockIdx.y, b = blockIdx.z;
  const float* Ab = v + (size_t)b * ((size_t)N_ * D_) + (size_t)(bm * 128) * D_;
  const u16* Bb = attnT + (size_t)b * ((size_t)D_ * D_) + (size_t)(bn * 128) * D_;
  float* C = out + (size_t)b * ((size_t)N_ * D_);
  const int tid = threadIdx.x;
  const int wave = tid >> 6, lane = tid & 63;
  const int wr = wave >> 1, wc = wave & 1;
  const int lrow = lane & 15, lk = (lane >> 4) * 8;
  const int srow = lane >> 2, scol = (lane & 3) * 8;
  const f32x4 fzero = {0.f, 0.f, 0.f, 0.f};
  f32x4 acc[4][4];
#pragma unroll
  for (int m = 0; m < 4; ++m)
#pragma unroll
    for (int n = 0; n < 4; ++n) acc[m][n] = fzero;

  for (int kt = 0; kt < 16; ++kt) {
    const int k0 = kt * 32;
    // A: 128 rows x 32 d fp32 -> bf16, one b128 write per thread per iter
    // (4 threads/row; slots (row&1, c8) cover all 8 16-B slots -> write floor)
#pragma unroll
    for (int i = 0; i < 2; ++i) {
      const int idx = i * 256 + tid;         // 0..511
      const int row = idx >> 2, c8 = idx & 3;
      const f32x4 f0 = *(const f32x4*)(Ab + (size_t)row * D_ + k0 + c8 * 8);
      const f32x4 f1 = *(const f32x4*)(Ab + (size_t)row * D_ + k0 + c8 * 8 + 4);
      bf16x8 o;
#pragma unroll
      for (int jj = 0; jj < 4; ++jj) {
        o[jj] = (__bf16)f0[jj];
        o[4 + jj] = (__bf16)f1[jj];
      }
      *(bf16x8*)(As + row * 32 + c8 * 8) = o;
    }
#pragma unroll
    for (int i = 0; i < 2; ++i) {
      const int cc = i * 4 + wave;
      load_lds16(Bb + (size_t)(cc * 16 + srow) * D_ + k0 + scol, Bs + cc * 512);
    }
    __syncthreads();
    bf16x8 af[4], bfv[4];
#pragma unroll
    for (int m = 0; m < 4; ++m)
      af[m] = *(const bf16x8*)(As + (wr * 64 + m * 16 + lrow) * 32 + lk);
#pragma unroll
    for (int n = 0; n < 4; ++n)
      bfv[n] = *(const bf16x8*)(Bs + (wc * 64 + n * 16 + lrow) * 32 + lk);
#pragma unroll
    for (int m = 0; m < 4; ++m)
#pragma unroll
      for (int n = 0; n < 4; ++n)
        acc[m][n] = __builtin_amdgcn_mfma_f32_16x16x32_bf16(af[m], bfv[n],
                                                            acc[m][n], 0, 0, 0);
    __syncthreads();
  }
  const int crow = (lane >> 4) * 4, ccol = lane & 15;
#pragma unroll
  for (int m = 0; m < 4; ++m) {
    const int grow = bm * 128 + wr * 64 + m * 16 + crow;
#pragma unroll
    for (int n = 0; n < 4; ++n) {
      const int gcol = bn * 128 + wc * 64 + n * 16 + ccol;
#pragma unroll
      for (int i2 = 0; i2 < 4; ++i2)
        C[(size_t)(grow + i2) * D_ + gcol] = acc[m][n][i2];
    }
  }
}

extern "C" void kernel_launch(void* const* d_in, const int* in_sizes, int n_in,
                              void* d_out, int out_size, void* d_ws, size_t ws_size,
                              hipStream_t stream) {
  const float* v = (const float*)d_in[0];
  const float* k = (const float*)d_in[1];
  float* out = (float*)d_out;                        // [8][4096][512] fp32, 64 MiB
  float* attn = out + (size_t)B_ * N_ * D_;          // [8][512][512] fp32, 8 MiB
  // Split-K partials: 8 x [8][512][512] f32 = 64 MiB = exactly the out region
  // (dead until gemm2 overwrites it).
  float* Sp = (float*)d_out;
  u16* attnT = (u16*)d_ws;                           // [8][512][512] bf16, 4 MiB

  k_gemm1f<<<dim3(4, 4, 64), dim3(256), 0, stream>>>(k, v, Sp);
  k_softmax<<<dim3(1024), dim3(256), 0, stream>>>(Sp, attn);
  k_attn_t<<<dim3(8, 8, 8), dim3(256), 0, stream>>>(attn, attnT);
  k_gemm2<<<dim3(32, 4, 8), dim3(256), 0, stream>>>(v, attnT, out);
}

// Round 6
// 90.049 us; speedup vs baseline: 1.3844x; 1.3844x over previous
//
#include <hip/hip_runtime.h>
#include <stdint.h>

#define B_ 8
#define N_ 4096
#define D_ 512
#define INV_T 0.04419417382415922f  // 1/sqrt(512)

typedef unsigned short u16;
typedef float f32x4 __attribute__((ext_vector_type(4)));
typedef __bf16 bf16x4 __attribute__((ext_vector_type(4)));
typedef __bf16 bf16x8 __attribute__((ext_vector_type(8)));
typedef unsigned short u16x8 __attribute__((ext_vector_type(8)));

__device__ __forceinline__ u16 f2bf(float x) {
  union { float f; uint32_t u; } c;
  c.f = x;
  uint32_t r = c.u + 0x7FFFu + ((c.u >> 16) & 1u);
  return (u16)(r >> 16);
}

__device__ __forceinline__ void load_lds16(const u16* g, u16* l) {
  __builtin_amdgcn_global_load_lds(
      (__attribute__((address_space(1))) void*)(g),
      (__attribute__((address_space(3))) void*)(l), 16, 0, 0);
}

// Fused transpose+gemm1: Sp[kz*8+b][d][e] = sum_{n in kz slice} k[b][n][d]*v[b][n][e]
// (unscaled; 1/T folded into softmax). Split-K=4. Double-buffered LDS,
// ONE barrier per K-step. XCD-swizzled 1D grid (512 blocks).
__global__ __launch_bounds__(256) void k_gemm1f(const float* __restrict__ kin,
                                                const float* __restrict__ vin,
                                                float* __restrict__ Sp) {
  __shared__ u16 As[2][128 * 32];  // [d_local][n_local], write-XOR-swizzled
  __shared__ u16 Bs[2][128 * 32];
  // XCD-aware swizzle: xcd = flat%8 gets 64 consecutive swz ids = 4 whole
  // z-slices -> slice (k+v, 4 MB) resident in that XCD's L2.
  const int flat = blockIdx.x;  // 0..511
  const int swz = (flat & 7) * 64 + (flat >> 3);
  const int z = swz >> 4;                      // 0..31
  const int bm = (swz >> 2) & 3, bn = swz & 3;
  const int b = z & 7, kz = z >> 3;            // split-K = 4, 1024 n per slice
  const int tid = threadIdx.x;
  const int wave = tid >> 6, lane = tid & 63;
  const int wr = wave >> 1, wc = wave & 1;
  const int lrow = lane & 15, lk = (lane >> 4) * 8;
  const int c = tid & 31, G = tid >> 5;  // c: d-chunk (4 cols), G: n-group
  const float* ga = kin + (size_t)b * N_ * D_ + (size_t)(kz * 1024 + 4 * G) * D_ +
                    bm * 128 + 4 * c;
  const float* gb = vin + (size_t)b * N_ * D_ + (size_t)(kz * 1024 + 4 * G) * D_ +
                    bn * 128 + 4 * c;
  float* C = Sp + (size_t)z * ((size_t)D_ * D_);

  const f32x4 fzero = {0.f, 0.f, 0.f, 0.f};
  f32x4 acc[4][4];
#pragma unroll
  for (int m = 0; m < 4; ++m)
#pragma unroll
    for (int n = 0; n < 4; ++n) acc[m][n] = fzero;

  f32x4 ra[4], rb[4];
#pragma unroll
  for (int j = 0; j < 4; ++j) {
    ra[j] = *(const f32x4*)(ga + (size_t)j * D_);
    rb[j] = *(const f32x4*)(gb + (size_t)j * D_);
  }

  for (int kt = 0; kt < 32; ++kt) {
    u16* Ab_ = As[kt & 1];
    u16* Bb_ = Bs[kt & 1];
    bf16x4 wav[4], wbv[4];  // register 4x4 transpose + cvt
#pragma unroll
    for (int i = 0; i < 4; ++i) {
#pragma unroll
      for (int j = 0; j < 4; ++j) {
        wav[i][j] = (__bf16)ra[j][i];
        wbv[i][j] = (__bf16)rb[j][i];
      }
    }
#pragma unroll
    for (int i = 0; i < 4; ++i) {
      // d_local = 4c+i; swizzle idx ^= ((d_local>>2)&7)<<3 == ((c&7)<<3)
      const int sidx = ((4 * c + i) * 32 + 4 * G) ^ ((c & 7) << 3);
      *(bf16x4*)(Ab_ + sidx) = wav[i];
      *(bf16x4*)(Bb_ + sidx) = wbv[i];
    }
    if (kt + 1 < 32) {
#pragma unroll
      for (int j = 0; j < 4; ++j) {  // prefetch next step into same reg set
        ra[j] = *(const f32x4*)(ga + (size_t)((kt + 1) * 32 + j) * D_);
        rb[j] = *(const f32x4*)(gb + (size_t)((kt + 1) * 32 + j) * D_);
      }
    }
    __syncthreads();  // single barrier: writes to buf[kt&1] visible
    bf16x8 af[4], bfv[4];
#pragma unroll
    for (int m = 0; m < 4; ++m) {
      const int row = wr * 64 + m * 16 + lrow;
      af[m] = *(const bf16x8*)(Ab_ + ((row * 32 + lk) ^ (((row >> 2) & 7) << 3)));
    }
#pragma unroll
    for (int n = 0; n < 4; ++n) {
      const int row = wc * 64 + n * 16 + lrow;
      bfv[n] = *(const bf16x8*)(Bb_ + ((row * 32 + lk) ^ (((row >> 2) & 7) << 3)));
    }
#pragma unroll
    for (int m = 0; m < 4; ++m)
#pragma unroll
      for (int n = 0; n < 4; ++n)
        acc[m][n] = __builtin_amdgcn_mfma_f32_16x16x32_bf16(af[m], bfv[n],
                                                            acc[m][n], 0, 0, 0);
    // no second barrier: next step writes the OTHER buffer; step kt+2's
    // writes to this buffer are fenced by barrier kt+1.
  }
  // C/D layout (m89-verified): row = (lane>>4)*4 + reg, col = lane&15
  const int crow = (lane >> 4) * 4, ccol = lane & 15;
#pragma unroll
  for (int m = 0; m < 4; ++m) {
    const int grow = bm * 128 + wr * 64 + m * 16 + crow;
#pragma unroll
    for (int n = 0; n < 4; ++n) {
      const int gcol = bn * 128 + wc * 64 + n * 16 + ccol;
#pragma unroll
      for (int i2 = 0; i2 < 4; ++i2)
        C[(size_t)(grow + i2) * D_ + gcol] = acc[m][n][i2];
    }
  }
}

// Sum 4 split-K partials, scale by 1/T, softmax rows, write attn fp32.
__global__ __launch_bounds__(256) void k_softmax(const float* __restrict__ Sp,
                                                 float* __restrict__ attn) {
  const int t = threadIdx.x;
  const int wave = t >> 6, lane = t & 63;
  const int g = blockIdx.x * 4 + wave;  // 0..4095 rows
  const int b = g >> 9, d = g & 511;
  const float* base = Sp + (size_t)b * (D_ * D_) + (size_t)d * D_ + lane * 8;
  float s[8];
#pragma unroll
  for (int jj = 0; jj < 8; ++jj) s[jj] = 0.f;
#pragma unroll
  for (int kz = 0; kz < 4; ++kz) {
    const f32x4 p0 = *(const f32x4*)(base + (size_t)kz * 8 * (D_ * D_));
    const f32x4 p1 = *(const f32x4*)(base + (size_t)kz * 8 * (D_ * D_) + 4);
#pragma unroll
    for (int jj = 0; jj < 4; ++jj) { s[jj] += p0[jj]; s[4 + jj] += p1[jj]; }
  }
#pragma unroll
  for (int jj = 0; jj < 8; ++jj) s[jj] *= INV_T;  // temperature
  float mx = s[0];
#pragma unroll
  for (int jj = 1; jj < 8; ++jj) mx = fmaxf(mx, s[jj]);
  for (int o = 32; o > 0; o >>= 1) mx = fmaxf(mx, __shfl_xor(mx, o));
  float sum = 0.f;
#pragma unroll
  for (int jj = 0; jj < 8; ++jj) { s[jj] = __expf(s[jj] - mx); sum += s[jj]; }
  for (int o = 32; o > 0; o >>= 1) sum += __shfl_xor(sum, o);
  const float inv = 1.0f / sum;
  float* orow = attn + (size_t)b * (D_ * D_) + (size_t)d * D_ + lane * 8;
  f32x4 o0, o1;
#pragma unroll
  for (int jj = 0; jj < 4; ++jj) { o0[jj] = s[jj] * inv; o1[jj] = s[4 + jj] * inv; }
  *(f32x4*)orow = o0;
  *(f32x4*)(orow + 4) = o1;
}

// attn fp32 [b][d][e] -> attnT bf16 [b][e][d]
__global__ __launch_bounds__(256) void k_attn_t(const float* __restrict__ attn,
                                                u16* __restrict__ attnT) {
  __shared__ float lds[64][65];
  const int t = threadIdx.x;
  const int b = blockIdx.z;
  const float* src = attn + (size_t)b * D_ * D_;
  u16* dst = attnT + (size_t)b * D_ * D_;
  const int d0 = blockIdx.x * 64, e0 = blockIdx.y * 64;
#pragma unroll
  for (int i = 0; i < 4; ++i) {
    const int fidx = i * 256 + t;
    const int r = fidx >> 4, c4 = fidx & 15;
    const f32x4 f = *(const f32x4*)(src + (size_t)(d0 + r) * D_ + e0 + c4 * 4);
#pragma unroll
    for (int jj = 0; jj < 4; ++jj) lds[r][c4 * 4 + jj] = f[jj];
  }
  __syncthreads();
#pragma unroll
  for (int j = 0; j < 2; ++j) {
    const int sidx = j * 256 + t;
    const int rd = sidx >> 3, c8 = sidx & 7;
    u16x8 o;
#pragma unroll
    for (int jj = 0; jj < 8; ++jj) o[jj] = f2bf(lds[c8 * 8 + jj][rd]);
    *(u16x8*)(dst + (size_t)(e0 + rd) * D_ + d0 + c8 * 8) = o;
  }
}

// gemm2: out[b][n][e] = sum_d v[b][n][d] * attnT[b][e][d]
// Double-buffered LDS, one barrier per step. A reg-staged fp32->bf16,
// B via global_load_lds (issued first for latency slack).
__global__ __launch_bounds__(256) void k_gemm2(const float* __restrict__ v,
                                               const u16* __restrict__ attnT,
                                               float* __restrict__ out) {
  __shared__ u16 As[2][128 * 32];
  __shared__ u16 Bs[2][128 * 32];
  const int bm = blockIdx.x, bn = blockIdx.y, b = blockIdx.z;
  const float* Ab = v + (size_t)b * ((size_t)N_ * D_) + (size_t)(bm * 128) * D_;
  const u16* Bb = attnT + (size_t)b * ((size_t)D_ * D_) + (size_t)(bn * 128) * D_;
  float* C = out + (size_t)b * ((size_t)N_ * D_);
  const int tid = threadIdx.x;
  const int wave = tid >> 6, lane = tid & 63;
  const int wr = wave >> 1, wc = wave & 1;
  const int lrow = lane & 15, lk = (lane >> 4) * 8;
  const int srow = lane >> 2, scol = (lane & 3) * 8;
  const int arow0 = tid >> 2, ac8 = tid & 3;  // A-staging: 4 threads/row
  const f32x4 fzero = {0.f, 0.f, 0.f, 0.f};
  f32x4 acc[4][4];
#pragma unroll
  for (int m = 0; m < 4; ++m)
#pragma unroll
    for (int n = 0; n < 4; ++n) acc[m][n] = fzero;

  f32x4 rf0[2], rf1[2];
#pragma unroll
  for (int i = 0; i < 2; ++i) {
    const int row = i * 64 + arow0;
    rf0[i] = *(const f32x4*)(Ab + (size_t)row * D_ + ac8 * 8);
    rf1[i] = *(const f32x4*)(Ab + (size_t)row * D_ + ac8 * 8 + 4);
  }

  for (int kt = 0; kt < 16; ++kt) {
    const int k0 = kt * 32;
    u16* Ad = As[kt & 1];
    u16* Bd = Bs[kt & 1];
    // B first: max slack before the barrier's vmcnt drain
#pragma unroll
    for (int i = 0; i < 2; ++i) {
      const int cc = i * 4 + wave;
      load_lds16(Bb + (size_t)(cc * 16 + srow) * D_ + k0 + scol, Bd + cc * 512);
    }
    // A: cvt staged regs -> one b128 write per thread per chunk
#pragma unroll
    for (int i = 0; i < 2; ++i) {
      const int row = i * 64 + arow0;
      bf16x8 o;
#pragma unroll
      for (int jj = 0; jj < 4; ++jj) {
        o[jj] = (__bf16)rf0[i][jj];
        o[4 + jj] = (__bf16)rf1[i][jj];
      }
      *(bf16x8*)(Ad + row * 32 + ac8 * 8) = o;
    }
    if (kt + 1 < 16) {
#pragma unroll
      for (int i = 0; i < 2; ++i) {
        const int row = i * 64 + arow0;
        rf0[i] = *(const f32x4*)(Ab + (size_t)row * D_ + (k0 + 32) + ac8 * 8);
        rf1[i] = *(const f32x4*)(Ab + (size_t)row * D_ + (k0 + 32) + ac8 * 8 + 4);
      }
    }
    __syncthreads();
    bf16x8 af[4], bfv[4];
#pragma unroll
    for (int m = 0; m < 4; ++m)
      af[m] = *(const bf16x8*)(Ad + (wr * 64 + m * 16 + lrow) * 32 + lk);
#pragma unroll
    for (int n = 0; n < 4; ++n)
      bfv[n] = *(const bf16x8*)(Bd + (wc * 64 + n * 16 + lrow) * 32 + lk);
#pragma unroll
    for (int m = 0; m < 4; ++m)
#pragma unroll
      for (int n = 0; n < 4; ++n)
        acc[m][n] = __builtin_amdgcn_mfma_f32_16x16x32_bf16(af[m], bfv[n],
                                                            acc[m][n], 0, 0, 0);
  }
  const int crow = (lane >> 4) * 4, ccol = lane & 15;
#pragma unroll
  for (int m = 0; m < 4; ++m) {
    const int grow = bm * 128 + wr * 64 + m * 16 + crow;
#pragma unroll
    for (int n = 0; n < 4; ++n) {
      const int gcol = bn * 128 + wc * 64 + n * 16 + ccol;
#pragma unroll
      for (int i2 = 0; i2 < 4; ++i2)
        C[(size_t)(grow + i2) * D_ + gcol] = acc[m][n][i2];
    }
  }
}

extern "C" void kernel_launch(void* const* d_in, const int* in_sizes, int n_in,
                              void* d_out, int out_size, void* d_ws, size_t ws_size,
                              hipStream_t stream) {
  const float* v = (const float*)d_in[0];
  const float* k = (const float*)d_in[1];
  float* out = (float*)d_out;                        // [8][4096][512] fp32, 64 MiB
  float* attn = out + (size_t)B_ * N_ * D_;          // [8][512][512] fp32, 8 MiB
  // Split-K partials: 4 x [8][512][512] f32 = 32 MiB in the out region
  // (dead until gemm2 overwrites it).
  float* Sp = (float*)d_out;
  u16* attnT = (u16*)d_ws;                           // [8][512][512] bf16, 4 MiB

  k_gemm1f<<<dim3(512), dim3(256), 0, stream>>>(k, v, Sp);
  k_softmax<<<dim3(1024), dim3(256), 0, stream>>>(Sp, attn);
  k_attn_t<<<dim3(8, 8, 8), dim3(256), 0, stream>>>(attn, attnT);
  k_gemm2<<<dim3(32, 4, 8), dim3(256), 0, stream>>>(v, attnT, out);
}